// Round 7
// baseline (114.598 us; speedup 1.0000x reference)
//
#include <hip/hip_runtime.h>

// SparseLookupTable via one-hot MFMA (data conventions HW-verified rounds 1-6):
//   out[b,o] = sum_k lut[inp[b,k], wgt[o,k]],  B=512, O=1024, K=128, LUT 256x256.
//   A_k[b, j] = lut[inp[b,k], j]   (f16 rows gathered from LDS, ds_read_b128)
//   B_k[j, o] = onehot(wgt[o,k])   (built in VALU registers)
// MFMA f32_16x16x32_f16, 8 K-steps of 32 cover the 256-wide one-hot dim.
//
// Round-7: round-6 ws path never ran (counters == atomic path, so ws_size < 4MB).
//   New combine needs only 2 MB of workspace: ksp=0 partial -> out (plain
//   stores, fully overwrites), ksp=1 partial -> d_ws, then out += ws kernel
//   (6 MB streaming ~2us). Fallback (ws < 2MB): verified zero+atomic path.
//   Compute hot loop byte-equivalent to the HW-verified round-5/6 kernel.

#define KDIM 128
#define OUT_FLOATS (512 * 1024)

typedef _Float16 f16x8 __attribute__((ext_vector_type(8)));
typedef float    f32x4 __attribute__((ext_vector_type(4)));

union F16Frag { uint4 u; f16x8 h; };

__global__ __launch_bounds__(256)
void zero_out(float* __restrict__ out) {
    ((float4*)out)[blockIdx.x * 256 + threadIdx.x] = float4{0.f, 0.f, 0.f, 0.f};
}

__global__ __launch_bounds__(256)
void combine_add(float* __restrict__ out, const float* __restrict__ ws) {
    int i = blockIdx.x * 256 + threadIdx.x;
    float4 a = ((const float4*)out)[i];
    float4 b = ((const float4*)ws)[i];
    ((float4*)out)[i] = float4{a.x + b.x, a.y + b.y, a.z + b.z, a.w + b.w};
}

__global__ __launch_bounds__(1024, 4)
void slt_mfma(const int* __restrict__ inp, const int* __restrict__ wgt,
              const float* __restrict__ lut, float* __restrict__ out,
              float* __restrict__ ws,
              const int mode /* 1: plain stores (ksp0->out, ksp1->ws); 0: atomics->out */)
{
    // 131072 (LUT f16 swizzled) + 2048 (i_lds [64][16] u16 row-pairs)
    // + 8192 (w_lds [64][16][8] u8) = 141312 B
    __shared__ __attribute__((aligned(16))) unsigned char smem[141312];
    unsigned char*  lutB  = smem;
    unsigned short* i_lds = (unsigned short*)(smem + 131072);
    unsigned char*  w_lds = (unsigned char*)(smem + 133120);

    const int tid   = threadIdx.x;
    const int otile = blockIdx.x;   // 8 tiles of 128 outputs
    const int btile = blockIdx.y;   // 16 tiles of 32 batch rows
    const int ksp   = blockIdx.z;   // 2 K-splits of 64 kslices

    // ---- stage LUT fp32 -> fp16, chunk-XOR swizzled (verbatim round 3) ----
    // row r, logical byte lb (512/row), chunk = lb>>4 (16B units).
    // phys = r*512 + (((chunk&24) | ((chunk ^ (r&7)) & 7)) << 4) + (lb & 15)
    {
        const float4* lut4 = (const float4*)lut;
        #pragma unroll
        for (int it = 0; it < 16; ++it) {
            int idx = it * 1024 + tid;
            float4 v = lut4[idx];
            union { _Float16 h[4]; unsigned long long u; } pk;
            pk.h[0] = (_Float16)v.x; pk.h[1] = (_Float16)v.y;
            pk.h[2] = (_Float16)v.z; pk.h[3] = (_Float16)v.w;
            unsigned r  = (unsigned)idx >> 6;
            unsigned lb = ((unsigned)idx & 63u) << 3;
            unsigned ch = lb >> 4;
            unsigned sw = (ch & 24u) | ((ch ^ (r & 7u)) & 7u);
            unsigned off = (r << 9) + (sw << 4) + (lb & 15u);
            *(unsigned long long*)(lutB + off) = pk.u;
        }
    }

    // ---- stage i: [ks][colq] u16 = (row colq | row colq+16 << 8), local ks ----
    if (tid < 512) {
        int row = tid >> 4;            // 0..31
        int c4  = tid & 15;            // int4 group within this block's 64 k's
        int4 iv = *(const int4*)(inp + (size_t)(btile * 32 + row) * KDIM
                                     + ksp * 64 + c4 * 4);
        unsigned char* ib = (unsigned char*)i_lds;
        int sub = row >> 4, r15 = row & 15;
        int ks0 = c4 * 4;
        ib[(ks0+0)*32 + r15*2 + sub] = (unsigned char)(iv.x & 255);
        ib[(ks0+1)*32 + r15*2 + sub] = (unsigned char)(iv.y & 255);
        ib[(ks0+2)*32 + r15*2 + sub] = (unsigned char)(iv.z & 255);
        ib[(ks0+3)*32 + r15*2 + sub] = (unsigned char)(iv.w & 255);
    }

    // ---- stage w: w_lds[ks*128 + colq*8 + nt] = wgt[otile*128+nt*16+colq][k] ----
    {
        int o  = tid >> 3;             // 0..127 output within tile
        int kq = tid & 7;              // octet of local ks
        const int* wp = wgt + (size_t)(otile * 128 + o) * KDIM + ksp * 64 + kq * 8;
        int4 w0 = *(const int4*)wp;
        int4 w1 = *(const int4*)(wp + 4);
        unsigned char* wb = w_lds + (o & 15) * 8 + (o >> 4);
        int ksb = kq * 8;
        wb[(ksb+0)*128] = (unsigned char)(w0.x & 255);
        wb[(ksb+1)*128] = (unsigned char)(w0.y & 255);
        wb[(ksb+2)*128] = (unsigned char)(w0.z & 255);
        wb[(ksb+3)*128] = (unsigned char)(w0.w & 255);
        wb[(ksb+4)*128] = (unsigned char)(w1.x & 255);
        wb[(ksb+5)*128] = (unsigned char)(w1.y & 255);
        wb[(ksb+6)*128] = (unsigned char)(w1.z & 255);
        wb[(ksb+7)*128] = (unsigned char)(w1.w & 255);
    }
    __syncthreads();

    const int      lane = tid & 63;
    const int      wid  = tid >> 6;                 // 4 kslices: wid*4 .. wid*4+3
    const unsigned colq = (unsigned)(lane & 15);    // A row-lane / B col / D col
    const unsigned q    = (unsigned)((lane >> 4) & 3);

    f32x4 acc[2][8];
    #pragma unroll
    for (int a = 0; a < 2; ++a)
        #pragma unroll
        for (int n = 0; n < 8; ++n) { f32x4 z = {0.f,0.f,0.f,0.f}; acc[a][n] = z; }

    #pragma unroll 1
    for (int jj = 0; jj < 4; ++jj) {
        const int ks = wid * 4 + jj;            // local kslice 0..63

        // A rows for both 16-row M-tiles (packed pair read)
        unsigned ip = i_lds[ks * 16 + colq];
        unsigned r0 = ip & 255u, r1 = ip >> 8;
        unsigned L0 = q ^ (r0 & 7u), L1 = q ^ (r1 & 7u);
        const unsigned char* pA0  = lutB + ((r0 << 9) + (L0 << 4));
        const unsigned char* pA1  = lutB + ((r1 << 9) + (L1 << 4));
        const unsigned char* pA0o = pA0 + 64u - ((L0 & 4u) << 5);
        const unsigned char* pA1o = pA1 + 64u - ((L1 & 4u) << 5);

        // One-hot prep for 8 N-tiles from one b64 read
        unsigned long long wq =
            *(const unsigned long long*)(w_lds + ks * 128 + colq * 8);
        unsigned wlo = (unsigned)wq, whi = (unsigned)(wq >> 32);

        unsigned k2[8], lo[8], hi[8];
        #pragma unroll
        for (int nt = 0; nt < 8; ++nt) {
            unsigned wv = ((nt < 4 ? wlo : whi) >> ((nt & 3) * 8)) & 255u;
            // wv bits: [7:5]=s*, [4:3]=owning k-group, [2:0]=slot
            // one-hot word: f16 1.0 at half (wv&1) of word (wv>>1)&1
            unsigned wd = 0x3C00u << ((wv & 1u) << 4);
            lo[nt] = (wv & 2u) ? 0u : wd;
            hi[nt] = (wv & 2u) ? wd : 0u;
            unsigned key = ((wv >> 4) & 0x0Eu) | ((wv >> 2) & 1u); // 2*s* + wordpair
            k2[nt] = (((wv >> 3) & 3u) == q) ? key : 0xFFu;       // sentinel if not ours
        }

        // 8 MFMA K-steps; each bb feeds both M-tiles, each A-read feeds 8 nt
        #pragma unroll
        for (int s = 0; s < 8; ++s) {
            const unsigned disp = (unsigned)(s >> 1) * 128u;
            F16Frag a0, a1;
            a0.u = *(const uint4*)(((s & 1) ? pA0o : pA0) + disp);
            a1.u = *(const uint4*)(((s & 1) ? pA1o : pA1) + disp);
            #pragma unroll
            for (int nt = 0; nt < 8; ++nt) {
                F16Frag bb;
                bool tA = (k2[nt] == 2u * (unsigned)s);
                bool tB = (k2[nt] == 2u * (unsigned)s + 1u);
                bb.u.x = tA ? lo[nt] : 0u;
                bb.u.y = tA ? hi[nt] : 0u;
                bb.u.z = tB ? lo[nt] : 0u;
                bb.u.w = tB ? hi[nt] : 0u;
                acc[0][nt] = __builtin_amdgcn_mfma_f32_16x16x32_f16(a0.h, bb.h, acc[0][nt], 0, 0, 0);
                acc[1][nt] = __builtin_amdgcn_mfma_f32_16x16x32_f16(a1.h, bb.h, acc[1][nt], 0, 0, 0);
            }
        }
    }

    // ---- cross-wave K-reduction in dead LUT LDS (2 phases), then writeout ----
    __syncthreads();                      // all waves done reading lutB
    float* outp = mode ? (ksp ? ws : out) : out;
    f32x4* red = (f32x4*)smem;            // 16 waves x 8 nt x 64 lanes = 128 KB
    #pragma unroll 1
    for (int mt = 0; mt < 2; ++mt) {
        #pragma unroll
        for (int nt = 0; nt < 8; ++nt)
            red[(wid * 8 + nt) * 64 + lane] = acc[mt][nt];
        __syncthreads();
        if (tid < 512) {
            const int nt = tid >> 6, ln = tid & 63;
            f32x4 s4 = {0.f, 0.f, 0.f, 0.f};
            #pragma unroll
            for (int w = 0; w < 16; ++w)
                s4 += red[(w * 8 + nt) * 64 + ln];
            // D layout: col = lane&15, row = (lane>>4)*4 + reg  (HW-verified)
            const int rrow = btile * 32 + mt * 16 + ((ln >> 4) & 3) * 4;
            const int ccol = otile * 128 + nt * 16 + (ln & 15);
            #pragma unroll
            for (int c = 0; c < 4; ++c) {
                size_t addr = (size_t)(rrow + c) * 1024 + ccol;
                if (mode) outp[addr] = s4[c];
                else      atomicAdd(&outp[addr], s4[c]);
            }
        }
        __syncthreads();                  // protect red before next phase
    }
}

extern "C" void kernel_launch(void* const* d_in, const int* in_sizes, int n_in,
                              void* d_out, int out_size, void* d_ws, size_t ws_size,
                              hipStream_t stream) {
    const int*   inp = (const int*)d_in[0];    // (512, 32, 4) int32
    const int*   wgt = (const int*)d_in[1];    // (1024, 32, 4) int32
    const float* lut = (const float*)d_in[2];  // (256, 256) fp32
    float*       out = (float*)d_out;          // (512, 1024) fp32

    dim3 grid(8, 16, 2);
    dim3 block(1024);

    if (ws_size >= (size_t)OUT_FLOATS * sizeof(float)) {
        // ksp0 partial -> out (plain stores, full overwrite), ksp1 -> ws,
        // then out += ws. Only 2 MB of workspace needed.
        float* ws = (float*)d_ws;
        slt_mfma<<<grid, block, 0, stream>>>(inp, wgt, lut, out, ws, 1);
        combine_add<<<dim3(512), dim3(256), 0, stream>>>(out, ws);
    } else {
        // fallback: zero + deterministic commutative atomics (verified r5/r6)
        zero_out<<<dim3(512), dim3(256), 0, stream>>>(out);
        slt_mfma<<<grid, block, 0, stream>>>(inp, wgt, lut, out, nullptr, 0);
    }
}

// Round 8
// 94.962 us; speedup vs baseline: 1.2068x; 1.2068x over previous
//
#include <hip/hip_runtime.h>

// SparseLookupTable via one-hot MFMA (data conventions HW-verified rounds 1-7):
//   out[b,o] = sum_k lut[inp[b,k], wgt[o,k]],  B=512, O=1024, K=128, LUT 256x256.
//   A_k[b, j] = lut[inp[b,k], j]   (f16 rows gathered from LDS, ds_read_b128)
//   B_k[j, o] = onehot(wgt[o,k])   (built in VALU registers)
// MFMA f32_16x16x32_f16, 8 K-steps of 32 cover the 256-wide one-hot dim.
//
// Round-8: kill the K-split (ws_size proven < 2MB twice; atomic combine was
//   100% of the overhang: 160MB HBM RMW traffic = the entire 60us runtime).
//   Tile 16(M) x 128(N), grid (8 otile, 32 btile) = 256 blocks, FULL K=128
//   in-block: 16 waves x 8 kslices each, reuse-8 A-reads unchanged (1024
//   b128/CU), one-shot 16-way LDS reduction, plain coalesced stores.
//   Single kernel launch. No atomics. No workspace.

#define KDIM 128

typedef _Float16 f16x8 __attribute__((ext_vector_type(8)));
typedef float    f32x4 __attribute__((ext_vector_type(4)));

union F16Frag { uint4 u; f16x8 h; };

__global__ __launch_bounds__(1024, 4)
void slt_mfma(const int* __restrict__ inp, const int* __restrict__ wgt,
              const float* __restrict__ lut, float* __restrict__ out)
{
    // 131072 (LUT f16 swizzled) + 2048 (i_lds [128][16] u8)
    // + 16384 (w_lds [128][16][8] u8) = 149504 B  (red reuses LUT region)
    __shared__ __attribute__((aligned(16))) unsigned char smem[149504];
    unsigned char* lutB  = smem;
    unsigned char* i_lds = smem + 131072;
    unsigned char* w_lds = smem + 133120;

    const int tid   = threadIdx.x;
    const int otile = blockIdx.x;   // 8 tiles of 128 outputs
    const int btile = blockIdx.y;   // 32 tiles of 16 batch rows

    // ---- stage LUT fp32 -> fp16, chunk-XOR swizzled (verbatim r3-r7) ----
    // row r, logical byte lb (512/row), chunk = lb>>4 (16B units).
    // phys = r*512 + (((chunk&24) | ((chunk ^ (r&7)) & 7)) << 4) + (lb & 15)
    {
        const float4* lut4 = (const float4*)lut;
        #pragma unroll
        for (int it = 0; it < 16; ++it) {
            int idx = it * 1024 + tid;
            float4 v = lut4[idx];
            union { _Float16 h[4]; unsigned long long u; } pk;
            pk.h[0] = (_Float16)v.x; pk.h[1] = (_Float16)v.y;
            pk.h[2] = (_Float16)v.z; pk.h[3] = (_Float16)v.w;
            unsigned r  = (unsigned)idx >> 6;
            unsigned lb = ((unsigned)idx & 63u) << 3;
            unsigned ch = lb >> 4;
            unsigned sw = (ch & 24u) | ((ch ^ (r & 7u)) & 7u);
            unsigned off = (r << 9) + (sw << 4) + (lb & 15u);
            *(unsigned long long*)(lutB + off) = pk.u;
        }
    }

    // ---- stage i: i_lds[k*16 + row] = inp[btile*16+row][k] & 255 ----
    if (tid < 512) {
        int row = tid >> 5;            // 0..15
        int c4  = tid & 31;            // int4 group over K=128
        int4 iv = *(const int4*)(inp + (size_t)(btile * 16 + row) * KDIM + c4 * 4);
        int k0 = c4 * 4;
        i_lds[(k0+0)*16 + row] = (unsigned char)(iv.x & 255);
        i_lds[(k0+1)*16 + row] = (unsigned char)(iv.y & 255);
        i_lds[(k0+2)*16 + row] = (unsigned char)(iv.z & 255);
        i_lds[(k0+3)*16 + row] = (unsigned char)(iv.w & 255);
    }

    // ---- stage w: w_lds[k*128 + colq*8 + nt] = wgt[otile*128+nt*16+colq][k] ----
    {
        int o  = tid >> 3;             // 0..127 output within tile
        int kq = tid & 7;              // 8 groups of 16 k each
        const int* wp = wgt + (size_t)(otile * 128 + o) * KDIM + kq * 16;
        unsigned char* wb = w_lds + (o & 15) * 8 + (o >> 4);
        #pragma unroll
        for (int g = 0; g < 4; ++g) {
            int4 wv4 = *(const int4*)(wp + g * 4);
            int kb = kq * 16 + g * 4;
            wb[(kb+0)*128] = (unsigned char)(wv4.x & 255);
            wb[(kb+1)*128] = (unsigned char)(wv4.y & 255);
            wb[(kb+2)*128] = (unsigned char)(wv4.z & 255);
            wb[(kb+3)*128] = (unsigned char)(wv4.w & 255);
        }
    }
    __syncthreads();

    const int      lane = tid & 63;
    const int      wid  = tid >> 6;                 // 8 kslices: wid*8 .. wid*8+7
    const unsigned colq = (unsigned)(lane & 15);    // A row-lane / B col / D col
    const unsigned q    = (unsigned)((lane >> 4) & 3);
    const unsigned h8   = q << 3;                   // k-subgroup * 8

    f32x4 acc[8];
    #pragma unroll
    for (int n = 0; n < 8; ++n) { f32x4 z = {0.f,0.f,0.f,0.f}; acc[n] = z; }

    #pragma unroll 1
    for (int j = 0; j < 8; ++j) {
        const int ks = wid * 8 + j;            // kslice 0..127 (full K)

        // A row for this lane's M-row (single 16-row M-tile)
        unsigned r0 = (unsigned)i_lds[ks * 16 + colq];
        unsigned L0 = q ^ (r0 & 7u);
        const unsigned char* pA  = lutB + ((r0 << 9) + (L0 << 4));
        const unsigned char* pAo = pA + 64u - ((L0 & 4u) << 5);

        // One-hot prep for 8 N-tiles from one b64 read (r3 sl/p scheme, verbatim)
        unsigned long long wq =
            *(const unsigned long long*)(w_lds + ks * 128 + colq * 8);
        unsigned wlo = (unsigned)wq, whi = (unsigned)(wq >> 32);

        unsigned p[8][4]; unsigned sl[8];
        #pragma unroll
        for (int nt = 0; nt < 8; ++nt) {
            unsigned wv = ((nt < 4 ? wlo : whi) >> ((nt & 3) * 8)) & 255u;
            unsigned u    = wv - h8;
            unsigned slot = u & 7u;
            unsigned long long pk = 0x3C00ULL << ((slot & 3u) << 4);
            unsigned lo = (unsigned)pk, hi = (unsigned)(pk >> 32);
            unsigned lh    = (slot < 4u);
            unsigned valid = ((u & 31u) < 8u);
            sl[nt] = valid ? (u >> 5) : 0xFFu;
            p[nt][0] = lh ? lo : 0u;
            p[nt][1] = lh ? hi : 0u;
            p[nt][2] = lh ? 0u : lo;
            p[nt][3] = lh ? 0u : hi;
        }

        // 8 MFMA K-steps; one A-read feeds all 8 nt
        #pragma unroll
        for (int s = 0; s < 8; ++s) {
            F16Frag a0;
            a0.u = *(const uint4*)((((unsigned)s & 1u) ? pAo : pA)
                                   + ((unsigned)s >> 1) * 128u);
            #pragma unroll
            for (int nt = 0; nt < 8; ++nt) {
                F16Frag bb;
                bool take = (sl[nt] == (unsigned)s);
                bb.u.x = take ? p[nt][0] : 0u;
                bb.u.y = take ? p[nt][1] : 0u;
                bb.u.z = take ? p[nt][2] : 0u;
                bb.u.w = take ? p[nt][3] : 0u;
                acc[nt] = __builtin_amdgcn_mfma_f32_16x16x32_f16(a0.h, bb.h, acc[nt], 0, 0, 0);
            }
        }
    }

    // ---- one-shot 16-way cross-wave reduction in dead LUT LDS + store ----
    __syncthreads();                      // all waves done reading lutB
    f32x4* red = (f32x4*)smem;            // [wid][nt][lane] = 16*8*64*16B = 128 KB
    #pragma unroll
    for (int nt = 0; nt < 8; ++nt)
        red[(wid * 8 + nt) * 64 + lane] = acc[nt];
    __syncthreads();

    if (tid < 512) {
        const int nt = tid >> 6, ln = tid & 63;
        f32x4 s4 = {0.f, 0.f, 0.f, 0.f};
        #pragma unroll
        for (int w = 0; w < 16; ++w)
            s4 += red[(w * 8 + nt) * 64 + ln];
        // D layout: col = lane&15, row = (lane>>4)*4 + reg  (HW-verified)
        const int rrow = btile * 16 + ((ln >> 4) & 3) * 4;
        const int ccol = otile * 128 + nt * 16 + (ln & 15);
        #pragma unroll
        for (int c = 0; c < 4; ++c)
            out[(size_t)(rrow + c) * 1024 + ccol] = s4[c];
    }
}

extern "C" void kernel_launch(void* const* d_in, const int* in_sizes, int n_in,
                              void* d_out, int out_size, void* d_ws, size_t ws_size,
                              hipStream_t stream) {
    const int*   inp = (const int*)d_in[0];    // (512, 32, 4) int32
    const int*   wgt = (const int*)d_in[1];    // (1024, 32, 4) int32
    const float* lut = (const float*)d_in[2];  // (256, 256) fp32
    float*       out = (float*)d_out;          // (512, 1024) fp32

    dim3 grid(8, 32);
    dim3 block(1024);
    slt_mfma<<<grid, block, 0, stream>>>(inp, wgt, lut, out);
}

// Round 9
// 94.633 us; speedup vs baseline: 1.2110x; 1.0035x over previous
//
#include <hip/hip_runtime.h>

// SparseLookupTable via one-hot MFMA (data conventions HW-verified rounds 1-8):
//   out[b,o] = sum_k lut[inp[b,k], wgt[o,k]],  B=512, O=1024, K=128, LUT 256x256.
//   A_k[b, j] = lut[inp[b,k], j]   (f16 rows gathered from LDS, ds_read_b128)
//   B_k[j, o] = onehot(wgt[o,k])   (built in VALU registers)
// MFMA f32_16x16x32_f16, 8 K-steps of 32 cover the 256-wide one-hot dim.
//
// Round-9: single change vs round-8 — force waves_per_eu(4,4).
//   Round-8 counters: VGPR_Count=64 (the 8-waves/EU boundary) although the
//   1024-thread/1-block-per-CU shape can only run 4 waves/EU. Theory: the
//   compiler register-capped at 64 for an occupancy we can't use, and
//   rematerialized the one-hot prep (p[8][4]+sl[8], ~40 regs of live state)
//   inside the 64-iter inner loop -> measured VALUBusy ~2x the instruction
//   model. waves_per_eu(4,4) unlocks the honest 128-VGPR budget.

#define KDIM 128

typedef _Float16 f16x8 __attribute__((ext_vector_type(8)));
typedef float    f32x4 __attribute__((ext_vector_type(4)));

union F16Frag { uint4 u; f16x8 h; };

__global__ __launch_bounds__(1024)
__attribute__((amdgpu_waves_per_eu(4, 4)))
void slt_mfma(const int* __restrict__ inp, const int* __restrict__ wgt,
              const float* __restrict__ lut, float* __restrict__ out)
{
    // 131072 (LUT f16 swizzled) + 2048 (i_lds [128][16] u8)
    // + 16384 (w_lds [128][16][8] u8) = 149504 B  (red reuses LUT region)
    __shared__ __attribute__((aligned(16))) unsigned char smem[149504];
    unsigned char* lutB  = smem;
    unsigned char* i_lds = smem + 131072;
    unsigned char* w_lds = smem + 133120;

    const int tid   = threadIdx.x;
    const int otile = blockIdx.x;   // 8 tiles of 128 outputs
    const int btile = blockIdx.y;   // 32 tiles of 16 batch rows

    // ---- stage LUT fp32 -> fp16, chunk-XOR swizzled (verbatim r3-r8) ----
    // row r, logical byte lb (512/row), chunk = lb>>4 (16B units).
    // phys = r*512 + (((chunk&24) | ((chunk ^ (r&7)) & 7)) << 4) + (lb & 15)
    {
        const float4* lut4 = (const float4*)lut;
        #pragma unroll
        for (int it = 0; it < 16; ++it) {
            int idx = it * 1024 + tid;
            float4 v = lut4[idx];
            union { _Float16 h[4]; unsigned long long u; } pk;
            pk.h[0] = (_Float16)v.x; pk.h[1] = (_Float16)v.y;
            pk.h[2] = (_Float16)v.z; pk.h[3] = (_Float16)v.w;
            unsigned r  = (unsigned)idx >> 6;
            unsigned lb = ((unsigned)idx & 63u) << 3;
            unsigned ch = lb >> 4;
            unsigned sw = (ch & 24u) | ((ch ^ (r & 7u)) & 7u);
            unsigned off = (r << 9) + (sw << 4) + (lb & 15u);
            *(unsigned long long*)(lutB + off) = pk.u;
        }
    }

    // ---- stage i: i_lds[k*16 + row] = inp[btile*16+row][k] & 255 ----
    if (tid < 512) {
        int row = tid >> 5;            // 0..15
        int c4  = tid & 31;            // int4 group over K=128
        int4 iv = *(const int4*)(inp + (size_t)(btile * 16 + row) * KDIM + c4 * 4);
        int k0 = c4 * 4;
        i_lds[(k0+0)*16 + row] = (unsigned char)(iv.x & 255);
        i_lds[(k0+1)*16 + row] = (unsigned char)(iv.y & 255);
        i_lds[(k0+2)*16 + row] = (unsigned char)(iv.z & 255);
        i_lds[(k0+3)*16 + row] = (unsigned char)(iv.w & 255);
    }

    // ---- stage w: w_lds[k*128 + colq*8 + nt] = wgt[otile*128+nt*16+colq][k] ----
    {
        int o  = tid >> 3;             // 0..127 output within tile
        int kq = tid & 7;              // 8 groups of 16 k each
        const int* wp = wgt + (size_t)(otile * 128 + o) * KDIM + kq * 16;
        unsigned char* wb = w_lds + (o & 15) * 8 + (o >> 4);
        #pragma unroll
        for (int g = 0; g < 4; ++g) {
            int4 wv4 = *(const int4*)(wp + g * 4);
            int kb = kq * 16 + g * 4;
            wb[(kb+0)*128] = (unsigned char)(wv4.x & 255);
            wb[(kb+1)*128] = (unsigned char)(wv4.y & 255);
            wb[(kb+2)*128] = (unsigned char)(wv4.z & 255);
            wb[(kb+3)*128] = (unsigned char)(wv4.w & 255);
        }
    }
    __syncthreads();

    const int      lane = tid & 63;
    const int      wid  = tid >> 6;                 // 8 kslices: wid*8 .. wid*8+7
    const unsigned colq = (unsigned)(lane & 15);    // A row-lane / B col / D col
    const unsigned q    = (unsigned)((lane >> 4) & 3);
    const unsigned h8   = q << 3;                   // k-subgroup * 8

    f32x4 acc[8];
    #pragma unroll
    for (int n = 0; n < 8; ++n) { f32x4 z = {0.f,0.f,0.f,0.f}; acc[n] = z; }

    #pragma unroll 1
    for (int j = 0; j < 8; ++j) {
        const int ks = wid * 8 + j;            // kslice 0..127 (full K)

        // A row for this lane's M-row (single 16-row M-tile)
        unsigned r0 = (unsigned)i_lds[ks * 16 + colq];
        unsigned L0 = q ^ (r0 & 7u);
        const unsigned char* pA  = lutB + ((r0 << 9) + (L0 << 4));
        const unsigned char* pAo = pA + 64u - ((L0 & 4u) << 5);

        // One-hot prep for 8 N-tiles from one b64 read (r3 sl/p scheme, verbatim)
        unsigned long long wq =
            *(const unsigned long long*)(w_lds + ks * 128 + colq * 8);
        unsigned wlo = (unsigned)wq, whi = (unsigned)(wq >> 32);

        unsigned p[8][4]; unsigned sl[8];
        #pragma unroll
        for (int nt = 0; nt < 8; ++nt) {
            unsigned wv = ((nt < 4 ? wlo : whi) >> ((nt & 3) * 8)) & 255u;
            unsigned u    = wv - h8;
            unsigned slot = u & 7u;
            unsigned long long pk = 0x3C00ULL << ((slot & 3u) << 4);
            unsigned lo = (unsigned)pk, hi = (unsigned)(pk >> 32);
            unsigned lh    = (slot < 4u);
            unsigned valid = ((u & 31u) < 8u);
            sl[nt] = valid ? (u >> 5) : 0xFFu;
            p[nt][0] = lh ? lo : 0u;
            p[nt][1] = lh ? hi : 0u;
            p[nt][2] = lh ? 0u : lo;
            p[nt][3] = lh ? 0u : hi;
        }

        // 8 MFMA K-steps; one A-read feeds all 8 nt
        #pragma unroll
        for (int s = 0; s < 8; ++s) {
            F16Frag a0;
            a0.u = *(const uint4*)((((unsigned)s & 1u) ? pAo : pA)
                                   + ((unsigned)s >> 1) * 128u);
            #pragma unroll
            for (int nt = 0; nt < 8; ++nt) {
                F16Frag bb;
                bool take = (sl[nt] == (unsigned)s);
                bb.u.x = take ? p[nt][0] : 0u;
                bb.u.y = take ? p[nt][1] : 0u;
                bb.u.z = take ? p[nt][2] : 0u;
                bb.u.w = take ? p[nt][3] : 0u;
                acc[nt] = __builtin_amdgcn_mfma_f32_16x16x32_f16(a0.h, bb.h, acc[nt], 0, 0, 0);
            }
        }
    }

    // ---- one-shot 16-way cross-wave reduction in dead LUT LDS + store ----
    __syncthreads();                      // all waves done reading lutB
    f32x4* red = (f32x4*)smem;            // [wid][nt][lane] = 16*8*64*16B = 128 KB
    #pragma unroll
    for (int nt = 0; nt < 8; ++nt)
        red[(wid * 8 + nt) * 64 + lane] = acc[nt];
    __syncthreads();

    if (tid < 512) {
        const int nt = tid >> 6, ln = tid & 63;
        f32x4 s4 = {0.f, 0.f, 0.f, 0.f};
        #pragma unroll
        for (int w = 0; w < 16; ++w)
            s4 += red[(w * 8 + nt) * 64 + ln];
        // D layout: col = lane&15, row = (lane>>4)*4 + reg  (HW-verified)
        const int rrow = btile * 16 + ((ln >> 4) & 3) * 4;
        const int ccol = otile * 128 + nt * 16 + (ln & 15);
        #pragma unroll
        for (int c = 0; c < 4; ++c)
            out[(size_t)(rrow + c) * 1024 + ccol] = s4[c];
    }
}

extern "C" void kernel_launch(void* const* d_in, const int* in_sizes, int n_in,
                              void* d_out, int out_size, void* d_ws, size_t ws_size,
                              hipStream_t stream) {
    const int*   inp = (const int*)d_in[0];    // (512, 32, 4) int32
    const int*   wgt = (const int*)d_in[1];    // (1024, 32, 4) int32
    const float* lut = (const float*)d_in[2];  // (256, 256) fp32
    float*       out = (float*)d_out;          // (512, 1024) fp32

    dim3 grid(8, 32);
    dim3 block(1024);
    slt_mfma<<<grid, block, 0, stream>>>(inp, wgt, lut, out);
}